// Round 1
// baseline (349.373 us; speedup 1.0000x reference)
//
#include <hip/hip_runtime.h>

typedef unsigned short u16;
typedef unsigned int u32;
typedef __attribute__((ext_vector_type(8))) short short8;
typedef __attribute__((ext_vector_type(4))) float f32x4;
typedef __attribute__((ext_vector_type(4))) u16 us4;

#define MFMA16(a,b,c) __builtin_amdgcn_mfma_f32_16x16x32_bf16(a,b,c,0,0,0)

__device__ __forceinline__ u16 f2b(float x){
  u32 u = __builtin_bit_cast(u32, x);
  u32 r = (u + 0x7fffu + ((u >> 16) & 1u)) >> 16;
  return (u16)r;
}

__device__ __forceinline__ void gll16(const u16* g, u16* l){
  __builtin_amdgcn_global_load_lds((const __attribute__((address_space(1))) u32*)g,
                                   (__attribute__((address_space(3))) u32*)l, 16, 0, 0);
}

// ---------------- f32 -> bf16 convert (vectorized) ----------------
__global__ __launch_bounds__(256) void k_conv(const float* __restrict__ x, u16* __restrict__ y, int n4){
  int i = blockIdx.x * 256 + threadIdx.x;
  if (i < n4){
    float4 v = reinterpret_cast<const float4*>(x)[i];
    us4 o; o.x = f2b(v.x); o.y = f2b(v.y); o.z = f2b(v.z); o.w = f2b(v.w);
    reinterpret_cast<us4*>(y)[i] = o;
  }
}

// ---------------- W [K][N] f32 -> WT [N][K] bf16 (optionally scaled) ----------------
__global__ __launch_bounds__(256) void k_transpose_w(const float* __restrict__ W, u16* __restrict__ WT,
                                                     int K, int N, float scale){
  __shared__ float t[32][33];
  int n0 = blockIdx.x * 32, k0 = blockIdx.y * 32;
  int tx = threadIdx.x & 31, ty = threadIdx.x >> 5;
  #pragma unroll
  for (int i = 0; i < 4; i++)
    t[ty + i*8][tx] = W[(size_t)(k0 + ty + i*8) * N + n0 + tx];
  __syncthreads();
  #pragma unroll
  for (int i = 0; i < 4; i++)
    WT[(size_t)(n0 + ty + i*8) * K + k0 + tx] = f2b(t[tx][ty + i*8] * scale);
}

// ---------------- V [4096][1024] bf16 -> VT [64 bh][64 d][1024 kv] bf16 ----------------
__global__ __launch_bounds__(256) void k_transpose_v(const u16* __restrict__ V, u16* __restrict__ VT){
  __shared__ u16 t[32][34];
  int kv0 = blockIdx.x * 32, d0 = blockIdx.y * 32, bh = blockIdx.z;
  int b = bh >> 4, h = bh & 15;
  int tx = threadIdx.x & 31, ty = threadIdx.x >> 5;
  #pragma unroll
  for (int i = 0; i < 4; i++)
    t[ty + i*8][tx] = V[(size_t)(b*1024 + kv0 + ty + i*8) * 1024 + h*64 + d0 + tx];
  __syncthreads();
  #pragma unroll
  for (int i = 0; i < 4; i++)
    VT[(size_t)bh * 65536 + (size_t)(d0 + ty + i*8) * 1024 + kv0 + tx] = t[tx][ty + i*8];
}

// ---------------- lambda per head ----------------
__global__ void k_lam(const float* __restrict__ q1, const float* __restrict__ k1,
                      const float* __restrict__ q2, const float* __restrict__ k2,
                      float* __restrict__ lam){
  int h = threadIdx.x;
  if (h < 16){
    float d1 = 0.f, d2 = 0.f;
    for (int i = 0; i < 64; i++){
      d1 += q1[h*64 + i] * k1[h*64 + i];
      d2 += q2[h*64 + i] * k2[h*64 + i];
    }
    lam[h] = expf(d1) - expf(d2) + 0.1f;
  }
}

// ---------------- GEMM: C[M][N] = A[M][K](bf16) * BT[N][K](bf16)^T ----------------
// 128x128 tile, BK=64, 4 waves (2x2), global_load_lds staging with pre-swizzled source.
template<bool OUTF32>
__global__ __launch_bounds__(256) void k_gemm(const u16* __restrict__ A, const u16* __restrict__ B,
                                              void* __restrict__ C, int M, int N, int K){
  __shared__ __align__(16) u16 As[128*64];
  __shared__ __align__(16) u16 Bs[128*64];
  const int tid = threadIdx.x;
  const int wave = tid >> 6, lane = tid & 63;
  const int lr = lane & 15, lg = lane >> 4;
  const int wm = wave >> 1, wn = wave & 1;
  const int m0 = blockIdx.y * 128, n0 = blockIdx.x * 128;

  f32x4 acc[4][4];
  #pragma unroll
  for (int i = 0; i < 4; i++)
    #pragma unroll
    for (int j = 0; j < 4; j++){ f32x4 z = {0.f,0.f,0.f,0.f}; acc[i][j] = z; }

  const int srow = tid >> 3;   // 0..31 (per issue, +32c)
  const int skc  = tid & 7;

  for (int k0 = 0; k0 < K; k0 += 64){
    #pragma unroll
    for (int c = 0; c < 4; c++){
      int row = c*32 + srow;
      const u16* ga = A + (size_t)(m0 + row) * K + k0 + ((skc ^ (row & 7)) << 3);
      gll16(ga, As + c*2048 + wave*512);
      const u16* gb = B + (size_t)(n0 + row) * K + k0 + ((skc ^ (row & 7)) << 3);
      gll16(gb, Bs + c*2048 + wave*512);
    }
    __syncthreads();
    #pragma unroll
    for (int kc = 0; kc < 2; kc++){
      short8 af[4], bfr[4];
      #pragma unroll
      for (int mt = 0; mt < 4; mt++){
        int row = wm*64 + mt*16 + lr;
        af[mt] = *reinterpret_cast<const short8*>(As + row*64 + (((kc*4 + lg) ^ (row & 7)) << 3));
      }
      #pragma unroll
      for (int nt = 0; nt < 4; nt++){
        int rown = wn*64 + nt*16 + lr;
        bfr[nt] = *reinterpret_cast<const short8*>(Bs + rown*64 + (((kc*4 + lg) ^ (rown & 7)) << 3));
      }
      #pragma unroll
      for (int mt = 0; mt < 4; mt++)
        #pragma unroll
        for (int nt = 0; nt < 4; nt++)
          acc[mt][nt] = MFMA16(af[mt], bfr[nt], acc[mt][nt]);
    }
    __syncthreads();
  }
  #pragma unroll
  for (int mt = 0; mt < 4; mt++)
    #pragma unroll
    for (int nt = 0; nt < 4; nt++)
      #pragma unroll
      for (int r = 0; r < 4; r++){
        int row = m0 + wm*64 + mt*16 + lg*4 + r;
        int col = n0 + wn*64 + nt*16 + lr;
        if (OUTF32) ((float*)C)[(size_t)row * N + col] = acc[mt][nt][r];
        else        ((u16*)C)[(size_t)row * N + col] = f2b(acc[mt][nt][r]);
      }
}

// ---------------- online softmax update (per wave, rows = 4*lg + r) ----------------
__device__ __forceinline__ void softmax_upd(f32x4 s[4], float m[4], float l[4], f32x4 o[4],
                                            u16* pl, int lr, int lg){
  float rmax[4];
  bool need = false;
  #pragma unroll
  for (int r = 0; r < 4; r++){
    float v = fmaxf(fmaxf(s[0][r], s[1][r]), fmaxf(s[2][r], s[3][r]));
    #pragma unroll
    for (int off = 1; off < 16; off <<= 1) v = fmaxf(v, __shfl_xor(v, off));
    rmax[r] = v;
    need = need || (v > m[r] + 8.0f);
  }
  if (__any(need)){
    #pragma unroll
    for (int r = 0; r < 4; r++){
      float nm = fmaxf(m[r], rmax[r]);
      float al = __expf(m[r] - nm);
      m[r] = nm; l[r] *= al;
      #pragma unroll
      for (int nt = 0; nt < 4; nt++) o[nt][r] *= al;
    }
  }
  #pragma unroll
  for (int r = 0; r < 4; r++){
    float sum = 0.f;
    #pragma unroll
    for (int nt = 0; nt < 4; nt++){
      float p = __expf(s[nt][r] - m[r]);
      s[nt][r] = p;
      sum += p;
    }
    #pragma unroll
    for (int off = 1; off < 16; off <<= 1) sum += __shfl_xor(sum, off);
    l[r] += sum;
  }
  #pragma unroll
  for (int nt = 0; nt < 4; nt++)
    #pragma unroll
    for (int r = 0; r < 4; r++)
      pl[(lg*4 + r)*88 + nt*16 + lr] = f2b(s[nt][r]);
}

// ---------------- differential flash attention ----------------
// Q [4096][2048] bf16 (SCALE pre-baked), K [4096][2048] bf16, VT [64][64][1024] bf16
// O [4096][1024] bf16 : O[b*1024+q][h*64+d] = sum att * V
__global__ __launch_bounds__(256) void k_attn(const u16* __restrict__ Q, const u16* __restrict__ Kb,
                                              const u16* __restrict__ VT, const float* __restrict__ lam,
                                              u16* __restrict__ O){
  int bid = blockIdx.x;
  int logical = (bid & 7) * 128 + (bid >> 3);          // XCD-chunked swizzle (1024 % 8 == 0)
  int qt = logical & 15, h = (logical >> 4) & 15, b = logical >> 8;
  const int tid = threadIdx.x, wave = tid >> 6, lane = tid & 63;
  const int lr = lane & 15, lg = lane >> 4;
  const int q0 = qt*64 + wave*16;

  __shared__ __align__(16) u16 Pl[4][2][16*88];
  u16* p1 = &Pl[wave][0][0];
  u16* p2 = &Pl[wave][1][0];

  const u16* Qp = Q + (size_t)(b*1024 + q0 + lr) * 2048 + h*128 + lg*8;
  short8 q1f[2], q2f[2];
  q1f[0] = *reinterpret_cast<const short8*>(Qp);
  q1f[1] = *reinterpret_cast<const short8*>(Qp + 32);
  q2f[0] = *reinterpret_cast<const short8*>(Qp + 64);
  q2f[1] = *reinterpret_cast<const short8*>(Qp + 96);

  const float lamh = lam[h];
  const u16* Kp = Kb + (size_t)(b*1024 + lr) * 2048 + h*128 + lg*8;
  const u16* Vp = VT + (size_t)(b*16 + h) * 65536 + (size_t)lr * 1024 + lg*8;

  f32x4 o1[4], o2[4];
  #pragma unroll
  for (int nt = 0; nt < 4; nt++){ f32x4 z = {0.f,0.f,0.f,0.f}; o1[nt] = z; o2[nt] = z; }
  float m1[4], l1[4], m2[4], l2[4];
  #pragma unroll
  for (int r = 0; r < 4; r++){ m1[r] = m2[r] = -3.0e38f; l1[r] = l2[r] = 0.f; }

  for (int kv0 = 0; kv0 < 1024; kv0 += 64){
    f32x4 s1[4], s2[4];
    #pragma unroll
    for (int nt = 0; nt < 4; nt++){ f32x4 z = {0.f,0.f,0.f,0.f}; s1[nt] = z; s2[nt] = z; }
    #pragma unroll
    for (int nt = 0; nt < 4; nt++){
      const u16* kp = Kp + (size_t)(kv0 + nt*16) * 2048;
      #pragma unroll
      for (int kc = 0; kc < 2; kc++){
        short8 kf1 = *reinterpret_cast<const short8*>(kp + kc*32);
        short8 kf2 = *reinterpret_cast<const short8*>(kp + 64 + kc*32);
        s1[nt] = MFMA16(q1f[kc], kf1, s1[nt]);
        s2[nt] = MFMA16(q2f[kc], kf2, s2[nt]);
      }
    }
    softmax_upd(s1, m1, l1, o1, p1, lr, lg);
    softmax_upd(s2, m2, l2, o2, p2, lr, lg);
    #pragma unroll
    for (int kc = 0; kc < 2; kc++){
      short8 pf1 = *reinterpret_cast<const short8*>(p1 + lr*88 + kc*32 + lg*8);
      short8 pf2 = *reinterpret_cast<const short8*>(p2 + lr*88 + kc*32 + lg*8);
      #pragma unroll
      for (int nt = 0; nt < 4; nt++){
        short8 vf = *reinterpret_cast<const short8*>(Vp + (size_t)(nt*16) * 1024 + kv0 + kc*32);
        o1[nt] = MFMA16(pf1, vf, o1[nt]);
        o2[nt] = MFMA16(pf2, vf, o2[nt]);
      }
    }
  }

  float inv1[4], inv2[4];
  #pragma unroll
  for (int r = 0; r < 4; r++){ inv1[r] = 1.0f / l1[r]; inv2[r] = lamh / l2[r]; }
  u16* Op = O + (size_t)(b*1024 + q0) * 1024 + h*64;
  #pragma unroll
  for (int nt = 0; nt < 4; nt++)
    #pragma unroll
    for (int r = 0; r < 4; r++){
      float v = o1[nt][r] * inv1[r] - o2[nt][r] * inv2[r];
      Op[(size_t)(lg*4 + r) * 1024 + nt*16 + lr] = f2b(v);
    }
}

// ---------------- launch ----------------
extern "C" void kernel_launch(void* const* d_in, const int* in_sizes, int n_in,
                              void* d_out, int out_size, void* d_ws, size_t ws_size,
                              hipStream_t stream){
  const float* Drift = (const float*)d_in[0];
  const float* Ocean = (const float*)d_in[1];
  const float* Wq    = (const float*)d_in[2];
  const float* Wk    = (const float*)d_in[3];
  const float* Wv    = (const float*)d_in[4];
  const float* Wo    = (const float*)d_in[5];
  const float* lq1   = (const float*)d_in[6];
  const float* lk1   = (const float*)d_in[7];
  const float* lq2   = (const float*)d_in[8];
  const float* lk2   = (const float*)d_in[9];
  float* out = (float*)d_out;

  char* ws = (char*)d_ws;
  u16* Xd  = (u16*)(ws);                       // 4096x1024 bf16
  u16* Xo  = (u16*)(ws + 8388608);             // 4096x1024
  u16* WqT = (u16*)(ws + 16777216);            // 2048x1024
  u16* WkT = (u16*)(ws + 20971520);            // 2048x1024
  u16* WvT = (u16*)(ws + 25165824);            // 1024x1024
  u16* WoT = (u16*)(ws + 27262976);            // 1024x1024
  u16* Qb  = (u16*)(ws + 29360128);            // 4096x2048
  u16* Kb  = (u16*)(ws + 46137344);            // 4096x2048
  u16* Vb  = (u16*)(ws + 62914560);            // 4096x1024
  u16* VTb = (u16*)(ws + 71303168);            // 64x64x1024
  u16* Ob  = (u16*)(ws + 79691776);            // 4096x1024
  float* lam = (float*)(ws + 88080384);        // 16 f32

  k_conv<<<4096, 256, 0, stream>>>(Drift, Xd, 1048576);
  k_conv<<<4096, 256, 0, stream>>>(Ocean, Xo, 1048576);
  k_transpose_w<<<dim3(64,32), 256, 0, stream>>>(Wq, WqT, 1024, 2048, 0.125f); // SCALE baked in
  k_transpose_w<<<dim3(64,32), 256, 0, stream>>>(Wk, WkT, 1024, 2048, 1.0f);
  k_transpose_w<<<dim3(32,32), 256, 0, stream>>>(Wv, WvT, 1024, 1024, 1.0f);
  k_transpose_w<<<dim3(32,32), 256, 0, stream>>>(Wo, WoT, 1024, 1024, 1.0f);
  k_gemm<false><<<dim3(16,32), 256, 0, stream>>>(Xd, WqT, Qb, 4096, 2048, 1024);
  k_gemm<false><<<dim3(16,32), 256, 0, stream>>>(Xo, WkT, Kb, 4096, 2048, 1024);
  k_gemm<false><<<dim3(8,32), 256, 0, stream>>>(Xo, WvT, Vb, 4096, 1024, 1024);
  k_transpose_v<<<dim3(32,2,64), 256, 0, stream>>>(Vb, VTb);
  k_lam<<<1, 64, 0, stream>>>(lq1, lk1, lq2, lk2, lam);
  k_attn<<<1024, 256, 0, stream>>>(Qb, Kb, VTb, lam, Ob);
  k_gemm<true><<<dim3(8,32), 256, 0, stream>>>(Ob, WoT, out, 4096, 1024, 1024);
}

// Round 2
// 332.285 us; speedup vs baseline: 1.0514x; 1.0514x over previous
//
#include <hip/hip_runtime.h>

typedef unsigned short u16;
typedef unsigned int u32;
typedef __attribute__((ext_vector_type(8))) short short8;
typedef __attribute__((ext_vector_type(4))) float f32x4;
typedef __attribute__((ext_vector_type(4))) u16 us4;

#define MFMA16(a,b,c) __builtin_amdgcn_mfma_f32_16x16x32_bf16(a,b,c,0,0,0)

__device__ __forceinline__ u16 f2b(float x){
  u32 u = __builtin_bit_cast(u32, x);
  u32 r = (u + 0x7fffu + ((u >> 16) & 1u)) >> 16;
  return (u16)r;
}

__device__ __forceinline__ void gll16(const u16* g, u16* l){
  __builtin_amdgcn_global_load_lds((const __attribute__((address_space(1))) u32*)g,
                                   (__attribute__((address_space(3))) u32*)l, 16, 0, 0);
}

// ---------------- f32 -> bf16 convert (vectorized) ----------------
__global__ __launch_bounds__(256) void k_conv(const float* __restrict__ x, u16* __restrict__ y, int n4){
  int i = blockIdx.x * 256 + threadIdx.x;
  if (i < n4){
    float4 v = reinterpret_cast<const float4*>(x)[i];
    us4 o; o.x = f2b(v.x); o.y = f2b(v.y); o.z = f2b(v.z); o.w = f2b(v.w);
    reinterpret_cast<us4*>(y)[i] = o;
  }
}

// ---------------- W [K][N] f32 -> WT [N][K] bf16 (optionally scaled) ----------------
__global__ __launch_bounds__(256) void k_transpose_w(const float* __restrict__ W, u16* __restrict__ WT,
                                                     int K, int N, float scale){
  __shared__ float t[32][33];
  int n0 = blockIdx.x * 32, k0 = blockIdx.y * 32;
  int tx = threadIdx.x & 31, ty = threadIdx.x >> 5;
  #pragma unroll
  for (int i = 0; i < 4; i++)
    t[ty + i*8][tx] = W[(size_t)(k0 + ty + i*8) * N + n0 + tx];
  __syncthreads();
  #pragma unroll
  for (int i = 0; i < 4; i++)
    WT[(size_t)(n0 + ty + i*8) * K + k0 + tx] = f2b(t[tx][ty + i*8] * scale);
}

// ---------------- V [4096][1024] bf16 -> VT [64 bh][64 d][1024 kv] bf16 ----------------
__global__ __launch_bounds__(256) void k_transpose_v(const u16* __restrict__ V, u16* __restrict__ VT){
  __shared__ u16 t[32][34];
  int kv0 = blockIdx.x * 32, d0 = blockIdx.y * 32, bh = blockIdx.z;
  int b = bh >> 4, h = bh & 15;
  int tx = threadIdx.x & 31, ty = threadIdx.x >> 5;
  #pragma unroll
  for (int i = 0; i < 4; i++)
    t[ty + i*8][tx] = V[(size_t)(b*1024 + kv0 + ty + i*8) * 1024 + h*64 + d0 + tx];
  __syncthreads();
  #pragma unroll
  for (int i = 0; i < 4; i++)
    VT[(size_t)bh * 65536 + (size_t)(d0 + ty + i*8) * 1024 + kv0 + tx] = t[tx][ty + i*8];
}

// ---------------- lambda per head ----------------
__global__ void k_lam(const float* __restrict__ q1, const float* __restrict__ k1,
                      const float* __restrict__ q2, const float* __restrict__ k2,
                      float* __restrict__ lam){
  int h = threadIdx.x;
  if (h < 16){
    float d1 = 0.f, d2 = 0.f;
    for (int i = 0; i < 64; i++){
      d1 += q1[h*64 + i] * k1[h*64 + i];
      d2 += q2[h*64 + i] * k2[h*64 + i];
    }
    lam[h] = expf(d1) - expf(d2) + 0.1f;
  }
}

// ---------------- GEMM: C[M][N] = A[M][K](bf16) * BT[N][K](bf16)^T ----------------
template<bool OUTF32>
__global__ __launch_bounds__(256) void k_gemm(const u16* __restrict__ A, const u16* __restrict__ B,
                                              void* __restrict__ C, int M, int N, int K){
  __shared__ __align__(16) u16 As[128*64];
  __shared__ __align__(16) u16 Bs[128*64];
  const int tid = threadIdx.x;
  const int wave = tid >> 6, lane = tid & 63;
  const int lr = lane & 15, lg = lane >> 4;
  const int wm = wave >> 1, wn = wave & 1;
  const int m0 = blockIdx.y * 128, n0 = blockIdx.x * 128;

  f32x4 acc[4][4];
  #pragma unroll
  for (int i = 0; i < 4; i++)
    #pragma unroll
    for (int j = 0; j < 4; j++){ f32x4 z = {0.f,0.f,0.f,0.f}; acc[i][j] = z; }

  const int srow = tid >> 3;
  const int skc  = tid & 7;

  for (int k0 = 0; k0 < K; k0 += 64){
    #pragma unroll
    for (int c = 0; c < 4; c++){
      int row = c*32 + srow;
      const u16* ga = A + (size_t)(m0 + row) * K + k0 + ((skc ^ (row & 7)) << 3);
      gll16(ga, As + c*2048 + wave*512);
      const u16* gb = B + (size_t)(n0 + row) * K + k0 + ((skc ^ (row & 7)) << 3);
      gll16(gb, Bs + c*2048 + wave*512);
    }
    __syncthreads();
    #pragma unroll
    for (int kc = 0; kc < 2; kc++){
      short8 af[4], bfr[4];
      #pragma unroll
      for (int mt = 0; mt < 4; mt++){
        int row = wm*64 + mt*16 + lr;
        af[mt] = *reinterpret_cast<const short8*>(As + row*64 + (((kc*4 + lg) ^ (row & 7)) << 3));
      }
      #pragma unroll
      for (int nt = 0; nt < 4; nt++){
        int rown = wn*64 + nt*16 + lr;
        bfr[nt] = *reinterpret_cast<const short8*>(Bs + rown*64 + (((kc*4 + lg) ^ (rown & 7)) << 3));
      }
      #pragma unroll
      for (int mt = 0; mt < 4; mt++)
        #pragma unroll
        for (int nt = 0; nt < 4; nt++)
          acc[mt][nt] = MFMA16(af[mt], bfr[nt], acc[mt][nt]);
    }
    __syncthreads();
  }
  #pragma unroll
  for (int mt = 0; mt < 4; mt++)
    #pragma unroll
    for (int nt = 0; nt < 4; nt++)
      #pragma unroll
      for (int r = 0; r < 4; r++){
        int row = m0 + wm*64 + mt*16 + lg*4 + r;
        int col = n0 + wn*64 + nt*16 + lr;
        if (OUTF32) ((float*)C)[(size_t)row * N + col] = acc[mt][nt][r];
        else        ((u16*)C)[(size_t)row * N + col] = f2b(acc[mt][nt][r]);
      }
}

// ---------------- in-lane online softmax (S^T layout: lane q = lr, 16 kv values) ----------------
// s[nt][r] holds S[kv = nt*16 + lg*4 + r][q = lr]. m,l are per-lane scalars for row q=lr.
// o[] is the O^T accumulator (also at q = lr), rescaled in place.
// Writes P^T as bf16 into pl ([16 q][64 kv], XOR-swizzled) for the PV B-fragment read.
__device__ __forceinline__ void softmax_t(f32x4 s[4], float& m, float& l, f32x4 o[4],
                                          u16* pl, int lr, int lg){
  float a0 = fmaxf(fmaxf(s[0][0], s[0][1]), fmaxf(s[0][2], s[0][3]));
  float a1 = fmaxf(fmaxf(s[1][0], s[1][1]), fmaxf(s[1][2], s[1][3]));
  float a2 = fmaxf(fmaxf(s[2][0], s[2][1]), fmaxf(s[2][2], s[2][3]));
  float a3 = fmaxf(fmaxf(s[3][0], s[3][1]), fmaxf(s[3][2], s[3][3]));
  float mx = fmaxf(fmaxf(a0, a1), fmaxf(a2, a3));
  mx = fmaxf(mx, __shfl_xor(mx, 16));
  mx = fmaxf(mx, __shfl_xor(mx, 32));
  if (__any(mx > m + 8.0f)){
    float nm = fmaxf(m, mx);
    float al = __expf(m - nm);
    m = nm; l *= al;
    #pragma unroll
    for (int nt = 0; nt < 4; nt++)
      #pragma unroll
      for (int r = 0; r < 4; r++) o[nt][r] *= al;
  }
  float sum = 0.f;
  #pragma unroll
  for (int nt = 0; nt < 4; nt++)
    #pragma unroll
    for (int r = 0; r < 4; r++){
      float p = __expf(s[nt][r] - m);
      s[nt][r] = p;
      sum += p;
    }
  sum += __shfl_xor(sum, 16);
  sum += __shfl_xor(sum, 32);
  l += sum;
  char* base = (char*)pl + lr * 128;
  const int swz = (lr & 7) << 4;
  #pragma unroll
  for (int nt = 0; nt < 4; nt++){
    us4 h;
    h.x = f2b(s[nt][0]); h.y = f2b(s[nt][1]); h.z = f2b(s[nt][2]); h.w = f2b(s[nt][3]);
    *reinterpret_cast<us4*>(base + (((nt*32 + lg*8) ^ swz))) = h;
  }
}

// ---------------- differential flash attention (transposed domain) ----------------
// Q [4096][2048] bf16 (SCALE baked), K [4096][2048] bf16, VT [64 bh][64 d][1024 kv] bf16
// O [4096][1024] bf16
__global__ __launch_bounds__(256) void k_attn(const u16* __restrict__ Q, const u16* __restrict__ Kb,
                                              const u16* __restrict__ VT, const float* __restrict__ lam,
                                              u16* __restrict__ O){
  int bid = blockIdx.x;
  int logical = (bid & 7) * 128 + (bid >> 3);          // XCD-chunked swizzle (1024 % 8 == 0)
  int qt = logical & 15, h = (logical >> 4) & 15, b = logical >> 8;
  const int tid = threadIdx.x, wave = tid >> 6, lane = tid & 63;
  const int lr = lane & 15, lg = lane >> 4;
  const int q0 = qt*64 + wave*16;

  __shared__ __align__(16) u16 Pl[4][2][16*64];        // 16 KB: per-wave P^T buffers
  u16* p1 = &Pl[wave][0][0];
  u16* p2 = &Pl[wave][1][0];
  const int swz = (lr & 7) << 4;

  // Q B-fragments: lane holds Q[q0+lr][kc*32 + lg*8 + j]
  const u16* Qp = Q + (size_t)(b*1024 + q0 + lr) * 2048 + h*128 + lg*8;
  short8 q1f[2], q2f[2];
  q1f[0] = *reinterpret_cast<const short8*>(Qp);
  q1f[1] = *reinterpret_cast<const short8*>(Qp + 32);
  q2f[0] = *reinterpret_cast<const short8*>(Qp + 64);
  q2f[1] = *reinterpret_cast<const short8*>(Qp + 96);

  const float lamh = lam[h];
  const u16* Kp = Kb + (size_t)(b*1024 + lr) * 2048 + h*128 + lg*8;
  const u16* Vp = VT + (size_t)(b*16 + h) * 65536 + (size_t)lr * 1024 + lg*8;

  f32x4 o1[4], o2[4];                                   // O^T: d = nt*16+lg*4+r, q = lr
  #pragma unroll
  for (int nt = 0; nt < 4; nt++){ f32x4 z = {0.f,0.f,0.f,0.f}; o1[nt] = z; o2[nt] = z; }
  float m1 = -3.0e38f, l1 = 0.f, m2 = -3.0e38f, l2 = 0.f;

  for (int kv0 = 0; kv0 < 1024; kv0 += 64){
    f32x4 s1[4], s2[4];
    #pragma unroll
    for (int nt = 0; nt < 4; nt++){ f32x4 z = {0.f,0.f,0.f,0.f}; s1[nt] = z; s2[nt] = z; }
    // S^T = K · Q^T : A-frag = K rows (kv), B-frag = Q rows (q)
    #pragma unroll
    for (int nt = 0; nt < 4; nt++){
      const u16* kp = Kp + (size_t)(kv0 + nt*16) * 2048;
      #pragma unroll
      for (int kc = 0; kc < 2; kc++){
        short8 kf1 = *reinterpret_cast<const short8*>(kp + kc*32);
        short8 kf2 = *reinterpret_cast<const short8*>(kp + 64 + kc*32);
        s1[nt] = MFMA16(kf1, q1f[kc], s1[nt]);
        s2[nt] = MFMA16(kf2, q2f[kc], s2[nt]);
      }
    }
    softmax_t(s1, m1, l1, o1, p1, lr, lg);
    softmax_t(s2, m2, l2, o2, p2, lr, lg);
    // O^T += V^T · P^T : A-frag = VT rows (d), B-frag = P^T (same lane layout as softmax)
    #pragma unroll
    for (int kc = 0; kc < 2; kc++){
      short8 pf1 = *reinterpret_cast<const short8*>((char*)p1 + lr*128 + (((kc*64 + lg*16) ^ swz)));
      short8 pf2 = *reinterpret_cast<const short8*>((char*)p2 + lr*128 + (((kc*64 + lg*16) ^ swz)));
      #pragma unroll
      for (int nt = 0; nt < 4; nt++){
        short8 vf = *reinterpret_cast<const short8*>(Vp + (size_t)(nt*16) * 1024 + kv0 + kc*32);
        o1[nt] = MFMA16(vf, pf1, o1[nt]);
        o2[nt] = MFMA16(vf, pf2, o2[nt]);
      }
    }
  }

  const float inv1 = 1.0f / l1;
  const float inv2 = lamh / l2;
  u16* Op = O + (size_t)(b*1024 + q0 + lr) * 1024 + h*64;
  #pragma unroll
  for (int nt = 0; nt < 4; nt++){
    us4 hh;
    #pragma unroll
    for (int r = 0; r < 4; r++){
      float v = o1[nt][r] * inv1 - o2[nt][r] * inv2;
      ((u16*)&hh)[r] = f2b(v);
    }
    *reinterpret_cast<us4*>(Op + nt*16 + lg*4) = hh;
  }
}

// ---------------- launch ----------------
extern "C" void kernel_launch(void* const* d_in, const int* in_sizes, int n_in,
                              void* d_out, int out_size, void* d_ws, size_t ws_size,
                              hipStream_t stream){
  const float* Drift = (const float*)d_in[0];
  const float* Ocean = (const float*)d_in[1];
  const float* Wq    = (const float*)d_in[2];
  const float* Wk    = (const float*)d_in[3];
  const float* Wv    = (const float*)d_in[4];
  const float* Wo    = (const float*)d_in[5];
  const float* lq1   = (const float*)d_in[6];
  const float* lk1   = (const float*)d_in[7];
  const float* lq2   = (const float*)d_in[8];
  const float* lk2   = (const float*)d_in[9];
  float* out = (float*)d_out;

  char* ws = (char*)d_ws;
  u16* Xd  = (u16*)(ws);                       // 4096x1024 bf16
  u16* Xo  = (u16*)(ws + 8388608);             // 4096x1024
  u16* WqT = (u16*)(ws + 16777216);            // 2048x1024
  u16* WkT = (u16*)(ws + 20971520);            // 2048x1024
  u16* WvT = (u16*)(ws + 25165824);            // 1024x1024
  u16* WoT = (u16*)(ws + 27262976);            // 1024x1024
  u16* Qb  = (u16*)(ws + 29360128);            // 4096x2048
  u16* Kb  = (u16*)(ws + 46137344);            // 4096x2048
  u16* Vb  = (u16*)(ws + 62914560);            // 4096x1024
  u16* VTb = (u16*)(ws + 71303168);            // 64x64x1024
  u16* Ob  = (u16*)(ws + 79691776);            // 4096x1024
  float* lam = (float*)(ws + 88080384);        // 16 f32

  k_conv<<<4096, 256, 0, stream>>>(Drift, Xd, 1048576);
  k_conv<<<4096, 256, 0, stream>>>(Ocean, Xo, 1048576);
  k_transpose_w<<<dim3(64,32), 256, 0, stream>>>(Wq, WqT, 1024, 2048, 0.125f);
  k_transpose_w<<<dim3(64,32), 256, 0, stream>>>(Wk, WkT, 1024, 2048, 1.0f);
  k_transpose_w<<<dim3(32,32), 256, 0, stream>>>(Wv, WvT, 1024, 1024, 1.0f);
  k_transpose_w<<<dim3(32,32), 256, 0, stream>>>(Wo, WoT, 1024, 1024, 1.0f);
  k_gemm<false><<<dim3(16,32), 256, 0, stream>>>(Xd, WqT, Qb, 4096, 2048, 1024);
  k_gemm<false><<<dim3(16,32), 256, 0, stream>>>(Xo, WkT, Kb, 4096, 2048, 1024);
  k_gemm<false><<<dim3(8,32), 256, 0, stream>>>(Xo, WvT, Vb, 4096, 1024, 1024);
  k_transpose_v<<<dim3(32,2,64), 256, 0, stream>>>(Vb, VTb);
  k_lam<<<1, 64, 0, stream>>>(lq1, lk1, lq2, lk2, lam);
  k_attn<<<1024, 256, 0, stream>>>(Qb, Kb, VTb, lam, Ob);
  k_gemm<true><<<dim3(8,32), 256, 0, stream>>>(Ob, WoT, out, 4096, 1024, 1024);
}

// Round 3
// 189.033 us; speedup vs baseline: 1.8482x; 1.7578x over previous
//
#include <hip/hip_runtime.h>

typedef unsigned short u16;
typedef unsigned int u32;
typedef __attribute__((ext_vector_type(8))) short short8;
typedef __attribute__((ext_vector_type(4))) float f32x4;
typedef __attribute__((ext_vector_type(4))) u16 us4;

#define MFMA16(a,b,c) __builtin_amdgcn_mfma_f32_16x16x32_bf16(a,b,c,0,0,0)

__device__ __forceinline__ u16 f2b(float x){
  u32 u = __builtin_bit_cast(u32, x);
  u32 r = (u + 0x7fffu + ((u >> 16) & 1u)) >> 16;
  return (u16)r;
}

__device__ __forceinline__ void gll16(const u16* g, u16* l){
  __builtin_amdgcn_global_load_lds((const __attribute__((address_space(1))) u32*)g,
                                   (__attribute__((address_space(3))) u32*)l, 16, 0, 0);
}

// ---------------- f32 -> bf16 convert (vectorized) ----------------
__global__ __launch_bounds__(256) void k_conv(const float* __restrict__ x, u16* __restrict__ y, int n4){
  int i = blockIdx.x * 256 + threadIdx.x;
  if (i < n4){
    float4 v = reinterpret_cast<const float4*>(x)[i];
    us4 o; o.x = f2b(v.x); o.y = f2b(v.y); o.z = f2b(v.z); o.w = f2b(v.w);
    reinterpret_cast<us4*>(y)[i] = o;
  }
}

// ---------------- W [K][N] f32 -> WT [N][K] bf16 (optionally scaled) ----------------
__global__ __launch_bounds__(256) void k_transpose_w(const float* __restrict__ W, u16* __restrict__ WT,
                                                     int K, int N, float scale){
  __shared__ float t[32][33];
  int n0 = blockIdx.x * 32, k0 = blockIdx.y * 32;
  int tx = threadIdx.x & 31, ty = threadIdx.x >> 5;
  #pragma unroll
  for (int i = 0; i < 4; i++)
    t[ty + i*8][tx] = W[(size_t)(k0 + ty + i*8) * N + n0 + tx];
  __syncthreads();
  #pragma unroll
  for (int i = 0; i < 4; i++)
    WT[(size_t)(n0 + ty + i*8) * K + k0 + tx] = f2b(t[tx][ty + i*8] * scale);
}

// ---------------- V [4096][1024] bf16 -> VT [64 bh][64 d][1024 kv] bf16 ----------------
__global__ __launch_bounds__(256) void k_transpose_v(const u16* __restrict__ V, u16* __restrict__ VT){
  __shared__ u16 t[32][34];
  int kv0 = blockIdx.x * 32, d0 = blockIdx.y * 32, bh = blockIdx.z;
  int b = bh >> 4, h = bh & 15;
  int tx = threadIdx.x & 31, ty = threadIdx.x >> 5;
  #pragma unroll
  for (int i = 0; i < 4; i++)
    t[ty + i*8][tx] = V[(size_t)(b*1024 + kv0 + ty + i*8) * 1024 + h*64 + d0 + tx];
  __syncthreads();
  #pragma unroll
  for (int i = 0; i < 4; i++)
    VT[(size_t)bh * 65536 + (size_t)(d0 + ty + i*8) * 1024 + kv0 + tx] = t[tx][ty + i*8];
}

// ---------------- lambda per head ----------------
__global__ void k_lam(const float* __restrict__ q1, const float* __restrict__ k1,
                      const float* __restrict__ q2, const float* __restrict__ k2,
                      float* __restrict__ lam){
  int h = threadIdx.x;
  if (h < 16){
    float d1 = 0.f, d2 = 0.f;
    for (int i = 0; i < 64; i++){
      d1 += q1[h*64 + i] * k1[h*64 + i];
      d2 += q2[h*64 + i] * k2[h*64 + i];
    }
    lam[h] = expf(d1) - expf(d2) + 0.1f;
  }
}

// ---------------- GEMM: C[M][N] = A[M][K](bf16) * BT[N][K](bf16)^T ----------------
template<bool OUTF32>
__global__ __launch_bounds__(256) void k_gemm(const u16* __restrict__ A, const u16* __restrict__ B,
                                              void* __restrict__ C, int M, int N, int K){
  __shared__ __align__(16) u16 As[128*64];
  __shared__ __align__(16) u16 Bs[128*64];
  const int tid = threadIdx.x;
  const int wave = tid >> 6, lane = tid & 63;
  const int lr = lane & 15, lg = lane >> 4;
  const int wm = wave >> 1, wn = wave & 1;
  const int m0 = blockIdx.y * 128, n0 = blockIdx.x * 128;

  f32x4 acc[4][4];
  #pragma unroll
  for (int i = 0; i < 4; i++)
    #pragma unroll
    for (int j = 0; j < 4; j++){ f32x4 z = {0.f,0.f,0.f,0.f}; acc[i][j] = z; }

  const int srow = tid >> 3;
  const int skc  = tid & 7;

  for (int k0 = 0; k0 < K; k0 += 64){
    #pragma unroll
    for (int c = 0; c < 4; c++){
      int row = c*32 + srow;
      const u16* ga = A + (size_t)(m0 + row) * K + k0 + ((skc ^ (row & 7)) << 3);
      gll16(ga, As + c*2048 + wave*512);
      const u16* gb = B + (size_t)(n0 + row) * K + k0 + ((skc ^ (row & 7)) << 3);
      gll16(gb, Bs + c*2048 + wave*512);
    }
    __syncthreads();
    #pragma unroll
    for (int kc = 0; kc < 2; kc++){
      short8 af[4], bfr[4];
      #pragma unroll
      for (int mt = 0; mt < 4; mt++){
        int row = wm*64 + mt*16 + lr;
        af[mt] = *reinterpret_cast<const short8*>(As + row*64 + (((kc*4 + lg) ^ (row & 7)) << 3));
      }
      #pragma unroll
      for (int nt = 0; nt < 4; nt++){
        int rown = wn*64 + nt*16 + lr;
        bfr[nt] = *reinterpret_cast<const short8*>(Bs + rown*64 + (((kc*4 + lg) ^ (rown & 7)) << 3));
      }
      #pragma unroll
      for (int mt = 0; mt < 4; mt++)
        #pragma unroll
        for (int nt = 0; nt < 4; nt++)
          acc[mt][nt] = MFMA16(af[mt], bfr[nt], acc[mt][nt]);
    }
    __syncthreads();
  }
  #pragma unroll
  for (int mt = 0; mt < 4; mt++)
    #pragma unroll
    for (int nt = 0; nt < 4; nt++)
      #pragma unroll
      for (int r = 0; r < 4; r++){
        int row = m0 + wm*64 + mt*16 + lg*4 + r;
        int col = n0 + wn*64 + nt*16 + lr;
        if (OUTF32) ((float*)C)[(size_t)row * N + col] = acc[mt][nt][r];
        else        ((u16*)C)[(size_t)row * N + col] = f2b(acc[mt][nt][r]);
      }
}

// ---------------- in-lane online softmax on S^T (lane q = lr) ----------------
// s[nt][r] = S^T[kv = nt*16+lg*4+r][q = lr]; m,l per-lane scalars; ob[nt][qt] is the
// O^T accumulator slice for this branch; writes P^T bf16 into pl [16 q][64 kv] swizzled.
__device__ __forceinline__ void softmax_t(f32x4 s[4], float& m, float& l, f32x4 (&ob)[4][2], int qt,
                                          u16* pl, int lr, int lg){
  float a0 = fmaxf(fmaxf(s[0][0], s[0][1]), fmaxf(s[0][2], s[0][3]));
  float a1 = fmaxf(fmaxf(s[1][0], s[1][1]), fmaxf(s[1][2], s[1][3]));
  float a2 = fmaxf(fmaxf(s[2][0], s[2][1]), fmaxf(s[2][2], s[2][3]));
  float a3 = fmaxf(fmaxf(s[3][0], s[3][1]), fmaxf(s[3][2], s[3][3]));
  float mx = fmaxf(fmaxf(a0, a1), fmaxf(a2, a3));
  mx = fmaxf(mx, __shfl_xor(mx, 16));
  mx = fmaxf(mx, __shfl_xor(mx, 32));
  if (__any(mx > m + 8.0f)){
    float nm = fmaxf(m, mx);
    float al = __expf(m - nm);
    m = nm; l *= al;
    #pragma unroll
    for (int nt = 0; nt < 4; nt++)
      #pragma unroll
      for (int r = 0; r < 4; r++) ob[nt][qt][r] *= al;
  }
  float sum = 0.f;
  #pragma unroll
  for (int nt = 0; nt < 4; nt++)
    #pragma unroll
    for (int r = 0; r < 4; r++){
      float p = __expf(s[nt][r] - m);
      s[nt][r] = p;
      sum += p;
    }
  sum += __shfl_xor(sum, 16);
  sum += __shfl_xor(sum, 32);
  l += sum;
  char* base = (char*)pl + lr * 128;
  const int swz = (lr & 7) << 4;
  #pragma unroll
  for (int nt = 0; nt < 4; nt++){
    us4 h;
    h.x = f2b(s[nt][0]); h.y = f2b(s[nt][1]); h.z = f2b(s[nt][2]); h.w = f2b(s[nt][3]);
    *reinterpret_cast<us4*>(base + ((nt*32 + lg*8) ^ swz)) = h;
  }
}

// ---------------- differential flash attention: LDS-staged K/V, 128q/block ----------------
// Q [4096][2048] bf16 (SCALE baked), K [4096][2048] bf16, VT [64 bh][64 d][1024 kv] bf16
// O [4096][1024] bf16. Grid 512: (qt 8) x (h 16) x (b 4), XCD-chunked.
__global__ __launch_bounds__(256, 2) void k_attn(const u16* __restrict__ Q, const u16* __restrict__ Kb,
                                                 const u16* __restrict__ VT, const float* __restrict__ lam,
                                                 u16* __restrict__ O){
  int bid = blockIdx.x;
  int logical = (bid & 7) * 64 + (bid >> 3);           // 512 % 8 == 0, bijective
  int qt8 = logical & 7, h = (logical >> 3) & 15, b = logical >> 7;
  const int tid = threadIdx.x, wave = tid >> 6, lane = tid & 63;
  const int lr = lane & 15, lg = lane >> 4;
  const int qb = qt8 * 128 + wave * 32;                // wave's 32 q-rows

  __shared__ __align__(16) u16 Ks[2][8192];            // [buf][64 kv][128 d] chunk-swizzled
  __shared__ __align__(16) u16 Vs[2][4096];            // [buf][64 d][64 kv] chunk-swizzled
  __shared__ __align__(16) u16 Pl[4][2][2][1024];      // [wave][qt][branch][16 q][64 kv]

  // ---- staging source pointers (global pre-swizzled so LDS dest stays linear) ----
  const int srow = tid >> 4, schunk = tid & 15;        // K tile: 64 rows x 16 chunks(16B)
  const int vrow = tid >> 3, vchunk = tid & 7;         // V tile: 64 rows x 8 chunks
  const u16* Kg = Kb + (size_t)(b*1024 + srow) * 2048 + h*128 + ((schunk ^ (srow & 7)) << 3);
  const u16* Vg = VT + (size_t)(b*16 + h) * 65536 + (size_t)vrow * 1024 + ((vchunk ^ (vrow & 7)) << 3);

  // ---- Q fragments (B-frag: lane holds Q[q][kc*32+lg*8..]) ----
  short8 qf[2][2][2];                                  // [branch][qt][kc]
  #pragma unroll
  for (int qt = 0; qt < 2; qt++){
    const u16* Qp = Q + (size_t)(b*1024 + qb + qt*16 + lr) * 2048 + h*128 + lg*8;
    #pragma unroll
    for (int kc = 0; kc < 2; kc++){
      qf[0][qt][kc] = *reinterpret_cast<const short8*>(Qp + kc*32);
      qf[1][qt][kc] = *reinterpret_cast<const short8*>(Qp + 64 + kc*32);
    }
  }
  const float lamh = lam[h];

  f32x4 o[2][4][2];                                    // [branch][nt(d)][qt]
  #pragma unroll
  for (int br = 0; br < 2; br++)
    #pragma unroll
    for (int nt = 0; nt < 4; nt++)
      #pragma unroll
      for (int qt = 0; qt < 2; qt++){ f32x4 z = {0.f,0.f,0.f,0.f}; o[br][nt][qt] = z; }
  float m[2][2], l[2][2];
  #pragma unroll
  for (int br = 0; br < 2; br++)
    #pragma unroll
    for (int qt = 0; qt < 2; qt++){ m[br][qt] = -3.0e38f; l[br][qt] = 0.f; }

  // ---- stage helper: 4 K-loads + 2 V-loads per thread, 24 KB per step ----
  auto STAGE = [&](int buf, int kv0){
    u16* kd = &Ks[buf][tid * 8];
    #pragma unroll
    for (int i = 0; i < 4; i++)
      gll16(Kg + (size_t)(kv0 + i*16) * 2048, kd + i*2048);
    u16* vd = &Vs[buf][tid * 8];
    #pragma unroll
    for (int j = 0; j < 2; j++)
      gll16(Vg + kv0 + (size_t)(j*32) * 1024, vd + j*2048);
  };

  STAGE(0, 0);
  __syncthreads();                                     // implicit vmcnt(0) drain

  for (int t = 0; t < 16; t++){
    const int cur = t & 1;
    if (t < 15) STAGE(cur ^ 1, (t + 1) << 6);          // prefetch next tile (in flight across compute)

    const u16* kbuf = &Ks[cur][0];
    const u16* vbuf = &Vs[cur][0];

    // ---- QK^T (S^T = K·Q^T) + softmax, branch-major ----
    #pragma unroll
    for (int br = 0; br < 2; br++){
      short8 kf[4][2];
      #pragma unroll
      for (int nt = 0; nt < 4; nt++)
        #pragma unroll
        for (int kc = 0; kc < 2; kc++)
          kf[nt][kc] = *reinterpret_cast<const short8*>(
              kbuf + (nt*16 + lr)*128 + (((br*8 + kc*4 + lg) ^ (lr & 7)) << 3));
      #pragma unroll
      for (int qt = 0; qt < 2; qt++){
        f32x4 s[4];
        #pragma unroll
        for (int nt = 0; nt < 4; nt++){ f32x4 z = {0.f,0.f,0.f,0.f}; s[nt] = z; }
        #pragma unroll
        for (int nt = 0; nt < 4; nt++)
          #pragma unroll
          for (int kc = 0; kc < 2; kc++)
            s[nt] = MFMA16(kf[nt][kc], qf[br][qt][kc], s[nt]);
        softmax_t(s, m[br][qt], l[br][qt], o[br], qt, &Pl[wave][qt][br][0], lr, lg);
      }
    }

    // ---- PV (O^T += V^T·P^T) ----
    const int swz = (lr & 7) << 4;
    #pragma unroll
    for (int kc = 0; kc < 2; kc++){
      short8 pf[2][2];                                 // [qt][branch]
      #pragma unroll
      for (int qt = 0; qt < 2; qt++)
        #pragma unroll
        for (int br = 0; br < 2; br++)
          pf[qt][br] = *reinterpret_cast<const short8*>(
              (char*)&Pl[wave][qt][br][0] + lr*128 + ((kc*64 + lg*16) ^ swz));
      #pragma unroll
      for (int nt = 0; nt < 4; nt++){
        short8 vf = *reinterpret_cast<const short8*>(
            vbuf + (nt*16 + lr)*64 + (((kc*4 + lg) ^ (lr & 7)) << 3));
        #pragma unroll
        for (int qt = 0; qt < 2; qt++){
          o[0][nt][qt] = MFMA16(vf, pf[qt][0], o[0][nt][qt]);
          o[1][nt][qt] = MFMA16(vf, pf[qt][1], o[1][nt][qt]);
        }
      }
    }
    __syncthreads();                                   // drains vmcnt(0): next tile staged
  }

  // ---- epilogue: O = O1/l1 - lam*O2/l2, write O^T slice (q on lr) ----
  #pragma unroll
  for (int qt = 0; qt < 2; qt++){
    const float inv1 = 1.0f / l[0][qt];
    const float inv2 = lamh / l[1][qt];
    u16* Op = O + (size_t)(b*1024 + qb + qt*16 + lr) * 1024 + h*64;
    #pragma unroll
    for (int nt = 0; nt < 4; nt++){
      us4 hh;
      #pragma unroll
      for (int r = 0; r < 4; r++){
        float v = o[0][nt][qt][r] * inv1 - o[1][nt][qt][r] * inv2;
        ((u16*)&hh)[r] = f2b(v);
      }
      *reinterpret_cast<us4*>(Op + nt*16 + lg*4) = hh;
    }
  }
}

// ---------------- launch ----------------
extern "C" void kernel_launch(void* const* d_in, const int* in_sizes, int n_in,
                              void* d_out, int out_size, void* d_ws, size_t ws_size,
                              hipStream_t stream){
  const float* Drift = (const float*)d_in[0];
  const float* Ocean = (const float*)d_in[1];
  const float* Wq    = (const float*)d_in[2];
  const float* Wk    = (const float*)d_in[3];
  const float* Wv    = (const float*)d_in[4];
  const float* Wo    = (const float*)d_in[5];
  const float* lq1   = (const float*)d_in[6];
  const float* lk1   = (const float*)d_in[7];
  const float* lq2   = (const float*)d_in[8];
  const float* lk2   = (const float*)d_in[9];
  float* out = (float*)d_out;

  char* ws = (char*)d_ws;
  u16* Xd  = (u16*)(ws);                       // 4096x1024 bf16
  u16* Xo  = (u16*)(ws + 8388608);             // 4096x1024
  u16* WqT = (u16*)(ws + 16777216);            // 2048x1024
  u16* WkT = (u16*)(ws + 20971520);            // 2048x1024
  u16* WvT = (u16*)(ws + 25165824);            // 1024x1024
  u16* WoT = (u16*)(ws + 27262976);            // 1024x1024
  u16* Qb  = (u16*)(ws + 29360128);            // 4096x2048
  u16* Kb  = (u16*)(ws + 46137344);            // 4096x2048
  u16* Vb  = (u16*)(ws + 62914560);            // 4096x1024
  u16* VTb = (u16*)(ws + 71303168);            // 64x64x1024
  u16* Ob  = (u16*)(ws + 79691776);            // 4096x1024
  float* lam = (float*)(ws + 88080384);        // 16 f32

  k_conv<<<4096, 256, 0, stream>>>(Drift, Xd, 1048576);
  k_conv<<<4096, 256, 0, stream>>>(Ocean, Xo, 1048576);
  k_transpose_w<<<dim3(64,32), 256, 0, stream>>>(Wq, WqT, 1024, 2048, 0.125f);
  k_transpose_w<<<dim3(64,32), 256, 0, stream>>>(Wk, WkT, 1024, 2048, 1.0f);
  k_transpose_w<<<dim3(32,32), 256, 0, stream>>>(Wv, WvT, 1024, 1024, 1.0f);
  k_transpose_w<<<dim3(32,32), 256, 0, stream>>>(Wo, WoT, 1024, 1024, 1.0f);
  k_gemm<false><<<dim3(16,32), 256, 0, stream>>>(Xd, WqT, Qb, 4096, 2048, 1024);
  k_gemm<false><<<dim3(16,32), 256, 0, stream>>>(Xo, WkT, Kb, 4096, 2048, 1024);
  k_gemm<false><<<dim3(8,32), 256, 0, stream>>>(Xo, WvT, Vb, 4096, 1024, 1024);
  k_transpose_v<<<dim3(32,2,64), 256, 0, stream>>>(Vb, VTb);
  k_lam<<<1, 64, 0, stream>>>(lq1, lk1, lq2, lk2, lam);
  k_attn<<<512, 256, 0, stream>>>(Qb, Kb, VTb, lam, Ob);
  k_gemm<true><<<dim3(8,32), 256, 0, stream>>>(Ob, WoT, out, 4096, 1024, 1024);
}

// Round 4
// 155.344 us; speedup vs baseline: 2.2490x; 1.2169x over previous
//
#include <hip/hip_runtime.h>
#include <hip/hip_bf16.h>

typedef unsigned short u16;
typedef unsigned int u32;
typedef __attribute__((ext_vector_type(8))) short short8;
typedef __attribute__((ext_vector_type(4))) float f32x4;
typedef __attribute__((ext_vector_type(4))) u16 us4;

#define MFMA16(a,b,c) __builtin_amdgcn_mfma_f32_16x16x32_bf16(a,b,c,0,0,0)

__device__ __forceinline__ u16 f2b(float x){
  u32 u = __builtin_bit_cast(u32, x);
  u32 r = (u + 0x7fffu + ((u >> 16) & 1u)) >> 16;
  return (u16)r;
}
// hardware cast (compiler pairs into v_cvt_pk_bf16_f32)
__device__ __forceinline__ u16 f2b_hw(float x){
  return __builtin_bit_cast(u16, __float2bfloat16(x));
}

__device__ __forceinline__ void gll16(const u16* g, u16* l){
  __builtin_amdgcn_global_load_lds((const __attribute__((address_space(1))) u32*)g,
                                   (__attribute__((address_space(3))) u32*)l, 16, 0, 0);
}

// ---------------- fused f32 -> bf16 convert for Drift+Ocean ----------------
__global__ __launch_bounds__(256) void k_conv2(const float* __restrict__ a, const float* __restrict__ bsrc,
                                               u16* __restrict__ ya, u16* __restrict__ yb){
  int bid = blockIdx.x;
  const float* x = (bid < 4096) ? a : bsrc;
  u16* y = (bid < 4096) ? ya : yb;
  int i = (bid & 4095) * 256 + threadIdx.x;
  float4 v = reinterpret_cast<const float4*>(x)[i];
  us4 o; o.x = f2b(v.x); o.y = f2b(v.y); o.z = f2b(v.z); o.w = f2b(v.w);
  reinterpret_cast<us4*>(y)[i] = o;
}

// ---------------- fused weight transposes + lambda ----------------
// z=0: Wq[1024][2048] -> WqT[2048][1024] *SCALE ; z=1: Wk -> WkvT rows 0..2047
// z=2: Wv[1024][1024] -> WkvT rows 2048..3071 ; z=3: Wo -> WoT (+ lam on block 0)
__global__ __launch_bounds__(256) void k_prep_w(const float* __restrict__ Wq, const float* __restrict__ Wk,
                                                const float* __restrict__ Wv, const float* __restrict__ Wo,
                                                u16* __restrict__ WqT, u16* __restrict__ WkvT,
                                                u16* __restrict__ WoT,
                                                const float* __restrict__ lq1, const float* __restrict__ lk1,
                                                const float* __restrict__ lq2, const float* __restrict__ lk2,
                                                float* __restrict__ lam){
  __shared__ float t[32][33];
  const int z = blockIdx.z;
  const float* W; u16* WT; int N; float scale = 1.0f;
  if (z == 0){ W = Wq; WT = WqT; N = 2048; scale = 0.125f; }
  else if (z == 1){ W = Wk; WT = WkvT; N = 2048; }
  else if (z == 2){ W = Wv; WT = WkvT + 2048*1024; N = 1024; }
  else { W = Wo; WT = WoT; N = 1024; }
  int n0 = blockIdx.x * 32, k0 = blockIdx.y * 32;
  int tx = threadIdx.x & 31, ty = threadIdx.x >> 5;
  if (n0 < N){
    #pragma unroll
    for (int i = 0; i < 4; i++)
      t[ty + i*8][tx] = W[(size_t)(k0 + ty + i*8) * N + n0 + tx];
    __syncthreads();
    #pragma unroll
    for (int i = 0; i < 4; i++)
      WT[(size_t)(n0 + ty + i*8) * 1024 + k0 + tx] = f2b(t[tx][ty + i*8] * scale);
  }
  if (z == 3 && blockIdx.x == 0 && blockIdx.y == 0 && threadIdx.x < 16){
    int h = threadIdx.x;
    float d1 = 0.f, d2 = 0.f;
    for (int i = 0; i < 64; i++){
      d1 += lq1[h*64 + i] * lk1[h*64 + i];
      d2 += lq2[h*64 + i] * lk2[h*64 + i];
    }
    lam[h] = expf(d1) - expf(d2) + 0.1f;
  }
}

// ---------------- V slice of KVb -> VT [64 bh][64 d][1024 kv] bf16 ----------------
__global__ __launch_bounds__(256) void k_transpose_v(const u16* __restrict__ KV, u16* __restrict__ VT){
  __shared__ u16 t[32][34];
  int kv0 = blockIdx.x * 32, d0 = blockIdx.y * 32, bh = blockIdx.z;
  int b = bh >> 4, h = bh & 15;
  int tx = threadIdx.x & 31, ty = threadIdx.x >> 5;
  #pragma unroll
  for (int i = 0; i < 4; i++)
    t[ty + i*8][tx] = KV[(size_t)(b*1024 + kv0 + ty + i*8) * 3072 + 2048 + h*64 + d0 + tx];
  __syncthreads();
  #pragma unroll
  for (int i = 0; i < 4; i++)
    VT[(size_t)bh * 65536 + (size_t)(d0 + ty + i*8) * 1024 + kv0 + tx] = t[tx][ty + i*8];
}

// ---------------- GEMM core (128x128 tile, BK=64, K=1024, bf16 A/B) ----------------
template<bool OUTF32>
__device__ __forceinline__ void gemm_body(const u16* __restrict__ A, const u16* __restrict__ B,
                                          void* __restrict__ C, int N, int m0, int n0,
                                          u16* As, u16* Bs){
  const int tid = threadIdx.x;
  const int wave = tid >> 6, lane = tid & 63;
  const int lr = lane & 15, lg = lane >> 4;
  const int wm = wave >> 1, wn = wave & 1;

  f32x4 acc[4][4];
  #pragma unroll
  for (int i = 0; i < 4; i++)
    #pragma unroll
    for (int j = 0; j < 4; j++){ f32x4 z = {0.f,0.f,0.f,0.f}; acc[i][j] = z; }

  const int srow = tid >> 3;
  const int skc  = tid & 7;

  for (int k0 = 0; k0 < 1024; k0 += 64){
    #pragma unroll
    for (int c = 0; c < 4; c++){
      int row = c*32 + srow;
      const u16* ga = A + (size_t)(m0 + row) * 1024 + k0 + ((skc ^ (row & 7)) << 3);
      gll16(ga, As + c*2048 + wave*512);
      const u16* gb = B + (size_t)(n0 + row) * 1024 + k0 + ((skc ^ (row & 7)) << 3);
      gll16(gb, Bs + c*2048 + wave*512);
    }
    __syncthreads();
    #pragma unroll
    for (int kc = 0; kc < 2; kc++){
      short8 af[4], bfr[4];
      #pragma unroll
      for (int mt = 0; mt < 4; mt++){
        int row = wm*64 + mt*16 + lr;
        af[mt] = *reinterpret_cast<const short8*>(As + row*64 + (((kc*4 + lg) ^ (row & 7)) << 3));
      }
      #pragma unroll
      for (int nt = 0; nt < 4; nt++){
        int rown = wn*64 + nt*16 + lr;
        bfr[nt] = *reinterpret_cast<const short8*>(Bs + rown*64 + (((kc*4 + lg) ^ (rown & 7)) << 3));
      }
      #pragma unroll
      for (int mt = 0; mt < 4; mt++)
        #pragma unroll
        for (int nt = 0; nt < 4; nt++)
          acc[mt][nt] = MFMA16(af[mt], bfr[nt], acc[mt][nt]);
    }
    __syncthreads();
  }
  #pragma unroll
  for (int mt = 0; mt < 4; mt++)
    #pragma unroll
    for (int nt = 0; nt < 4; nt++)
      #pragma unroll
      for (int r = 0; r < 4; r++){
        int row = m0 + wm*64 + mt*16 + lg*4 + r;
        int col = n0 + wn*64 + nt*16 + lr;
        if (OUTF32) ((float*)C)[(size_t)row * N + col] = acc[mt][nt][r];
        else        ((u16*)C)[(size_t)row * N + col] = f2b(acc[mt][nt][r]);
      }
}

// fused projection GEMM: bid<512 -> Q = Xd*WqT^T [4096][2048]; else KV = Xo*WkvT^T [4096][3072]
__global__ __launch_bounds__(256) void k_gemm_proj(const u16* __restrict__ Xd, const u16* __restrict__ Xo,
                                                   const u16* __restrict__ WqT, const u16* __restrict__ WkvT,
                                                   u16* __restrict__ Qb, u16* __restrict__ KVb){
  __shared__ __align__(16) u16 As[128*64];
  __shared__ __align__(16) u16 Bs[128*64];
  int bid = blockIdx.x;
  if (bid < 512){
    gemm_body<false>(Xd, WqT, Qb, 2048, (bid >> 4) * 128, (bid & 15) * 128, As, Bs);
  } else {
    int t = bid - 512;
    gemm_body<false>(Xo, WkvT, KVb, 3072, (t / 24) * 128, (t % 24) * 128, As, Bs);
  }
}

// output GEMM: out = Ob * WoT^T, f32 out
__global__ __launch_bounds__(256) void k_gemm_out(const u16* __restrict__ A, const u16* __restrict__ B,
                                                  float* __restrict__ C){
  __shared__ __align__(16) u16 As[128*64];
  __shared__ __align__(16) u16 Bs[128*64];
  int bid = blockIdx.x;
  gemm_body<true>(A, B, C, 1024, (bid >> 3) * 128, (bid & 7) * 128, As, Bs);
}

// ---------------- in-lane online softmax on S^T (lane q = lr) ----------------
__device__ __forceinline__ void softmax_t(f32x4 s[4], float& m, float& l, f32x4 (&ob)[4][2], int qt,
                                          u16* pl, int lr, int lg){
  float a0 = fmaxf(fmaxf(s[0][0], s[0][1]), fmaxf(s[0][2], s[0][3]));
  float a1 = fmaxf(fmaxf(s[1][0], s[1][1]), fmaxf(s[1][2], s[1][3]));
  float a2 = fmaxf(fmaxf(s[2][0], s[2][1]), fmaxf(s[2][2], s[2][3]));
  float a3 = fmaxf(fmaxf(s[3][0], s[3][1]), fmaxf(s[3][2], s[3][3]));
  float mx = fmaxf(fmaxf(a0, a1), fmaxf(a2, a3));
  mx = fmaxf(mx, __shfl_xor(mx, 16));
  mx = fmaxf(mx, __shfl_xor(mx, 32));
  if (__any(mx > m + 8.0f)){
    float nm = fmaxf(m, mx);
    float al = __expf(m - nm);
    m = nm; l *= al;
    #pragma unroll
    for (int nt = 0; nt < 4; nt++)
      #pragma unroll
      for (int r = 0; r < 4; r++) ob[nt][qt][r] *= al;
  }
  float sum = 0.f;
  #pragma unroll
  for (int nt = 0; nt < 4; nt++)
    #pragma unroll
    for (int r = 0; r < 4; r++){
      float p = __expf(s[nt][r] - m);
      s[nt][r] = p;
      sum += p;
    }
  sum += __shfl_xor(sum, 16);
  sum += __shfl_xor(sum, 32);
  l += sum;
  char* base = (char*)pl + lr * 128;
  const int swz = (lr & 7) << 4;
  #pragma unroll
  for (int nt = 0; nt < 4; nt++){
    us4 h;
    h.x = f2b_hw(s[nt][0]); h.y = f2b_hw(s[nt][1]);
    h.z = f2b_hw(s[nt][2]); h.w = f2b_hw(s[nt][3]);
    *reinterpret_cast<us4*>(base + ((nt*32 + lg*8) ^ swz)) = h;
  }
}

// ---------------- differential flash attention: LDS-staged K/V, 128q/block ----------------
// Q [4096][2048] bf16 (SCALE baked), KV [4096][3072] bf16 (K = cols 0..2047),
// VT [64 bh][64 d][1024 kv] bf16, O [4096][1024] bf16. Grid 512.
__global__ __launch_bounds__(256, 2) void k_attn(const u16* __restrict__ Q, const u16* __restrict__ KVb,
                                                 const u16* __restrict__ VT, const float* __restrict__ lam,
                                                 u16* __restrict__ O){
  int bid = blockIdx.x;
  int logical = (bid & 7) * 64 + (bid >> 3);           // 512 % 8 == 0, bijective
  int qt8 = logical & 7, h = (logical >> 3) & 15, b = logical >> 7;
  const int tid = threadIdx.x, wave = tid >> 6, lane = tid & 63;
  const int lr = lane & 15, lg = lane >> 4;
  const int qb = qt8 * 128 + wave * 32;

  __shared__ __align__(16) u16 Ks[2][8192];            // [buf][64 kv][128 d] chunk-swizzled
  __shared__ __align__(16) u16 Vs[2][4096];            // [buf][64 d][64 kv] chunk-swizzled
  __shared__ __align__(16) u16 Pl[4][2][2][1024];      // [wave][qt][branch][16 q][64 kv]

  const int srow = tid >> 4, schunk = tid & 15;
  const int vrow = tid >> 3, vchunk = tid & 7;
  const u16* Kg = KVb + (size_t)(b*1024 + srow) * 3072 + h*128 + ((schunk ^ (srow & 7)) << 3);
  const u16* Vg = VT + (size_t)(b*16 + h) * 65536 + (size_t)vrow * 1024 + ((vchunk ^ (vrow & 7)) << 3);

  short8 qf[2][2][2];                                  // [branch][qt][kc]
  #pragma unroll
  for (int qt = 0; qt < 2; qt++){
    const u16* Qp = Q + (size_t)(b*1024 + qb + qt*16 + lr) * 2048 + h*128 + lg*8;
    #pragma unroll
    for (int kc = 0; kc < 2; kc++){
      qf[0][qt][kc] = *reinterpret_cast<const short8*>(Qp + kc*32);
      qf[1][qt][kc] = *reinterpret_cast<const short8*>(Qp + 64 + kc*32);
    }
  }
  const float lamh = lam[h];

  f32x4 o[2][4][2];
  #pragma unroll
  for (int br = 0; br < 2; br++)
    #pragma unroll
    for (int nt = 0; nt < 4; nt++)
      #pragma unroll
      for (int qt = 0; qt < 2; qt++){ f32x4 z = {0.f,0.f,0.f,0.f}; o[br][nt][qt] = z; }
  float m[2][2], l[2][2];
  #pragma unroll
  for (int br = 0; br < 2; br++)
    #pragma unroll
    for (int qt = 0; qt < 2; qt++){ m[br][qt] = -3.0e38f; l[br][qt] = 0.f; }

  auto STAGE = [&](int buf, int kv0){
    u16* kd = &Ks[buf][tid * 8];
    #pragma unroll
    for (int i = 0; i < 4; i++)
      gll16(Kg + (size_t)(kv0 + i*16) * 3072, kd + i*2048);
    u16* vd = &Vs[buf][tid * 8];
    #pragma unroll
    for (int j = 0; j < 2; j++)
      gll16(Vg + kv0 + (size_t)(j*32) * 1024, vd + j*2048);
  };

  STAGE(0, 0);
  __syncthreads();

  for (int t = 0; t < 16; t++){
    const int cur = t & 1;
    if (t < 15) STAGE(cur ^ 1, (t + 1) << 6);

    const u16* kbuf = &Ks[cur][0];
    const u16* vbuf = &Vs[cur][0];

    #pragma unroll
    for (int br = 0; br < 2; br++){
      short8 kf[4][2];
      #pragma unroll
      for (int nt = 0; nt < 4; nt++)
        #pragma unroll
        for (int kc = 0; kc < 2; kc++)
          kf[nt][kc] = *reinterpret_cast<const short8*>(
              kbuf + (nt*16 + lr)*128 + (((br*8 + kc*4 + lg) ^ (lr & 7)) << 3));
      #pragma unroll
      for (int qt = 0; qt < 2; qt++){
        f32x4 s[4];
        #pragma unroll
        for (int nt = 0; nt < 4; nt++){ f32x4 z = {0.f,0.f,0.f,0.f}; s[nt] = z; }
        #pragma unroll
        for (int nt = 0; nt < 4; nt++)
          #pragma unroll
          for (int kc = 0; kc < 2; kc++)
            s[nt] = MFMA16(kf[nt][kc], qf[br][qt][kc], s[nt]);
        softmax_t(s, m[br][qt], l[br][qt], o[br], qt, &Pl[wave][qt][br][0], lr, lg);
      }
    }

    const int swz = (lr & 7) << 4;
    #pragma unroll
    for (int kc = 0; kc < 2; kc++){
      short8 pf[2][2];
      #pragma unroll
      for (int qt = 0; qt < 2; qt++)
        #pragma unroll
        for (int br = 0; br < 2; br++)
          pf[qt][br] = *reinterpret_cast<const short8*>(
              (char*)&Pl[wave][qt][br][0] + lr*128 + ((kc*64 + lg*16) ^ swz));
      #pragma unroll
      for (int nt = 0; nt < 4; nt++){
        short8 vf = *reinterpret_cast<const short8*>(
            vbuf + (nt*16 + lr)*64 + (((kc*4 + lg) ^ (lr & 7)) << 3));
        #pragma unroll
        for (int qt = 0; qt < 2; qt++){
          o[0][nt][qt] = MFMA16(vf, pf[qt][0], o[0][nt][qt]);
          o[1][nt][qt] = MFMA16(vf, pf[qt][1], o[1][nt][qt]);
        }
      }
    }
    __syncthreads();
  }

  #pragma unroll
  for (int qt = 0; qt < 2; qt++){
    const float inv1 = 1.0f / l[0][qt];
    const float inv2 = lamh / l[1][qt];
    u16* Op = O + (size_t)(b*1024 + qb + qt*16 + lr) * 1024 + h*64;
    #pragma unroll
    for (int nt = 0; nt < 4; nt++){
      us4 hh;
      #pragma unroll
      for (int r = 0; r < 4; r++){
        float v = o[0][nt][qt][r] * inv1 - o[1][nt][qt][r] * inv2;
        ((u16*)&hh)[r] = f2b_hw(v);
      }
      *reinterpret_cast<us4*>(Op + nt*16 + lg*4) = hh;
    }
  }
}

// ---------------- launch ----------------
extern "C" void kernel_launch(void* const* d_in, const int* in_sizes, int n_in,
                              void* d_out, int out_size, void* d_ws, size_t ws_size,
                              hipStream_t stream){
  const float* Drift = (const float*)d_in[0];
  const float* Ocean = (const float*)d_in[1];
  const float* Wq    = (const float*)d_in[2];
  const float* Wk    = (const float*)d_in[3];
  const float* Wv    = (const float*)d_in[4];
  const float* Wo    = (const float*)d_in[5];
  const float* lq1   = (const float*)d_in[6];
  const float* lk1   = (const float*)d_in[7];
  const float* lq2   = (const float*)d_in[8];
  const float* lk2   = (const float*)d_in[9];
  float* out = (float*)d_out;

  char* ws = (char*)d_ws;
  u16* Xd   = (u16*)(ws);                      // 4096x1024 bf16
  u16* Xo   = (u16*)(ws + 8388608);            // 4096x1024
  u16* WqT  = (u16*)(ws + 16777216);           // 2048x1024
  u16* WkvT = (u16*)(ws + 20971520);           // 3072x1024
  u16* WoT  = (u16*)(ws + 27262976);           // 1024x1024
  u16* Qb   = (u16*)(ws + 29360128);           // 4096x2048
  u16* KVb  = (u16*)(ws + 46137344);           // 4096x3072
  u16* VTb  = (u16*)(ws + 71303168);           // 64x64x1024
  u16* Ob   = (u16*)(ws + 79691776);           // 4096x1024
  float* lam = (float*)(ws + 88080384);        // 16 f32

  k_conv2<<<8192, 256, 0, stream>>>(Drift, Ocean, Xd, Xo);
  k_prep_w<<<dim3(64,32,4), 256, 0, stream>>>(Wq, Wk, Wv, Wo, WqT, WkvT, WoT,
                                              lq1, lk1, lq2, lk2, lam);
  k_gemm_proj<<<1280, 256, 0, stream>>>(Xd, Xo, WqT, WkvT, Qb, KVb);
  k_transpose_v<<<dim3(32,2,64), 256, 0, stream>>>(KVb, VTb);
  k_attn<<<512, 256, 0, stream>>>(Qb, KVb, VTb, lam, Ob);
  k_gemm_out<<<256, 256, 0, stream>>>(Ob, WoT, out);
}